// Round 1
// baseline (76.806 us; speedup 1.0000x reference)
//
#include <hip/hip_runtime.h>
#include <cfloat>
#include <cmath>

// Problem constants (from reference): x[B,W,L], shapelets[N,L], cls_w[1,N], cls_b[1]
constexpr int B = 64;
constexpr int W = 256;
constexpr int N = 128;
constexpr int L = 64;

// Kernel 1: per-(b, window-chunk) squared-distance + partial min over windows.
// grid = B * NCHUNKS, block = 256 (= N lanes x 2 window-slots).
// part layout: part[b][c][n], c in [0, NCHUNKS)
template <int NCHUNKS>
__global__ __launch_bounds__(256) void shapelet_min_kernel(
    const float* __restrict__ x, const float* __restrict__ shp,
    float* __restrict__ part) {
  constexpr int WPB = W / NCHUNKS;          // windows per block
  __shared__ float xs[WPB * L];             // 8 KB at NCHUNKS=8

  const int blk = blockIdx.x;
  const int b = blk / NCHUNKS;
  const int c = blk % NCHUNKS;
  const int tid = threadIdx.x;
  const int n = tid & (N - 1);              // shapelet index for this thread
  const int wslot = tid >> 7;               // 0 or 1: which half of the windows

  // Stage x[b, c*WPB:(c+1)*WPB, :] into LDS, coalesced float4.
  {
    const float4* xg =
        (const float4*)(x + (size_t)b * W * L + (size_t)c * WPB * L);
    float4* xls = (float4*)xs;
    constexpr int NV4 = WPB * L / 4;
    for (int i = tid; i < NV4; i += 256) xls[i] = xg[i];
  }

  // Shapelet row n -> registers (64 VGPRs). 32 KB table is L1/L2 resident.
  float s[L];
  {
    const float4* sg = (const float4*)(shp + (size_t)n * L);
#pragma unroll
    for (int i = 0; i < L / 4; ++i) {
      float4 v = sg[i];
      s[4 * i + 0] = v.x;
      s[4 * i + 1] = v.y;
      s[4 * i + 2] = v.z;
      s[4 * i + 3] = v.w;
    }
  }

  __syncthreads();

  // Each thread: min over its WPB/2 windows of sum_l (x - s)^2.
  float best = FLT_MAX;
  const int w0 = wslot * (WPB / 2);
  for (int wi = 0; wi < WPB / 2; ++wi) {
    const float* xr = xs + (size_t)(w0 + wi) * L;
    float a0 = 0.f, a1 = 0.f, a2 = 0.f, a3 = 0.f;  // 4 chains for ILP
#pragma unroll
    for (int l = 0; l < L; l += 4) {
      // All 64 lanes of a wave read the same address -> LDS broadcast (free).
      float4 xv = *(const float4*)(xr + l);
      float d0 = xv.x - s[l + 0]; a0 = fmaf(d0, d0, a0);
      float d1 = xv.y - s[l + 1]; a1 = fmaf(d1, d1, a1);
      float d2 = xv.z - s[l + 2]; a2 = fmaf(d2, d2, a2);
      float d3 = xv.w - s[l + 3]; a3 = fmaf(d3, d3, a3);
    }
    best = fminf(best, (a0 + a1) + (a2 + a3));
  }

  // Combine the two window-slots per shapelet via LDS (reuse xs).
  __syncthreads();
  if (wslot == 1) xs[n] = best;
  __syncthreads();
  if (wslot == 0) {
    part[((size_t)b * NCHUNKS + c) * N + n] = fminf(best, xs[n]);
  }
}

// Kernel 2: min over chunks -> sqrt -> dot(cls_w) -> sigmoid.
// grid = B, block = 128 (one thread per shapelet).
template <int NCHUNKS>
__global__ __launch_bounds__(128) void shapelet_head_kernel(
    const float* __restrict__ part, const float* __restrict__ cls_w,
    const float* __restrict__ cls_b, float* __restrict__ out) {
  const int b = blockIdx.x;
  const int n = threadIdx.x;  // 0..127

  float m = FLT_MAX;
#pragma unroll
  for (int c = 0; c < NCHUNKS; ++c)
    m = fminf(m, part[((size_t)b * NCHUNKS + c) * N + n]);

  float v = sqrtf(m) * cls_w[n];

  // Sum over 128 threads: wave64 shuffle reduce, then combine 2 waves in LDS.
#pragma unroll
  for (int off = 32; off > 0; off >>= 1) v += __shfl_down(v, off, 64);

  __shared__ float red[2];
  if ((n & 63) == 0) red[n >> 6] = v;
  __syncthreads();
  if (n == 0) {
    float z = red[0] + red[1] + cls_b[0];
    out[b] = 1.0f / (1.0f + expf(-z));
  }
}

template <int NCHUNKS>
static void launch_impl(const float* x, const float* shp, const float* cls_w,
                        const float* cls_b, float* out, float* part,
                        hipStream_t stream) {
  shapelet_min_kernel<NCHUNKS>
      <<<B * NCHUNKS, 256, 0, stream>>>(x, shp, part);
  shapelet_head_kernel<NCHUNKS>
      <<<B, 128, 0, stream>>>(part, cls_w, cls_b, out);
}

extern "C" void kernel_launch(void* const* d_in, const int* in_sizes, int n_in,
                              void* d_out, int out_size, void* d_ws,
                              size_t ws_size, hipStream_t stream) {
  const float* x = (const float*)d_in[0];        // [B, W, L]
  const float* shp = (const float*)d_in[1];      // [N, L]
  const float* cls_w = (const float*)d_in[2];    // [1, N]
  const float* cls_b = (const float*)d_in[3];    // [1]
  float* out = (float*)d_out;                    // [B, 1]
  float* part = (float*)d_ws;                    // [B, NCHUNKS, N]

  const size_t per_chunk = (size_t)B * N * sizeof(float);  // 32 KB
  if (ws_size >= 8 * per_chunk) {
    launch_impl<8>(x, shp, cls_w, cls_b, out, part, stream);
  } else if (ws_size >= 4 * per_chunk) {
    launch_impl<4>(x, shp, cls_w, cls_b, out, part, stream);
  } else if (ws_size >= 2 * per_chunk) {
    launch_impl<2>(x, shp, cls_w, cls_b, out, part, stream);
  } else {
    launch_impl<1>(x, shp, cls_w, cls_b, out, part, stream);
  }
}

// Round 2
// 71.840 us; speedup vs baseline: 1.0691x; 1.0691x over previous
//
#include <hip/hip_runtime.h>
#include <cfloat>
#include <cmath>

// x[B,W,L], shapelets[N,L], cls_w[1,N], cls_b[1]
constexpr int B = 64;
constexpr int W = 256;
constexpr int N = 128;
constexpr int L = 64;

// Kernel 1: per-(b, window-chunk), compute  min_w( ||x_w||^2 - 2<x_w, s_n> )
// for every shapelet n. ||s_n||^2 is added in kernel 2 (min commutes with it).
// grid = B*NCHUNKS, block = 256 (= N lanes x 2 window-slots).
template <int NCHUNKS>
__global__ __launch_bounds__(256) void shapelet_min_kernel(
    const float* __restrict__ x, const float* __restrict__ shp,
    float* __restrict__ part) {
  constexpr int WPB = W / NCHUNKS;     // windows per block (16 at NCHUNKS=16)
  constexpr int NV4 = WPB * L / 4;     // float4s to stage (256 at NCHUNKS=16)
  __shared__ float xs[WPB * L];        // 4 KB at NCHUNKS=16
  __shared__ float xnorm_s[WPB];
  __shared__ float comb[N];

  const int b = blockIdx.x / NCHUNKS;
  const int c = blockIdx.x % NCHUNKS;
  const int tid = threadIdx.x;
  const int n = tid & (N - 1);   // shapelet owned by this thread
  const int wslot = tid >> 7;    // 0/1: which half of the windows

  const float4* xg =
      (const float4*)(x + ((size_t)b * W + (size_t)c * WPB) * L);
  float4* xls = (float4*)xs;

  if constexpr (NV4 == 256) {
    // One float4 per thread; window w = tid>>4 (16 float4 per window).
    // Fused staging + ||x_w||^2 via 16-lane shuffle reduction.
    float4 v = xg[tid];
    xls[tid] = v;
    float p = v.x * v.x + v.y * v.y + v.z * v.z + v.w * v.w;
    p += __shfl_xor(p, 8, 16);
    p += __shfl_xor(p, 4, 16);
    p += __shfl_xor(p, 2, 16);
    p += __shfl_xor(p, 1, 16);
    if ((tid & 15) == 0) xnorm_s[tid >> 4] = p;
  } else {
    // Generic fallback: LDS atomic accumulation of window norms.
    if (tid < WPB) xnorm_s[tid] = 0.f;
    __syncthreads();
    for (int i = tid; i < NV4; i += 256) {
      float4 v = xg[i];
      xls[i] = v;
      float p = v.x * v.x + v.y * v.y + v.z * v.z + v.w * v.w;
      atomicAdd(&xnorm_s[i >> 4], p);
    }
  }

  // Shapelet row n -> 64 VGPRs (32 KB table, L1/L2 resident across blocks).
  float s[L];
  {
    const float4* sg = (const float4*)(shp + (size_t)n * L);
#pragma unroll
    for (int i = 0; i < L / 4; ++i) {
      float4 v = sg[i];
      s[4 * i + 0] = v.x;
      s[4 * i + 1] = v.y;
      s[4 * i + 2] = v.z;
      s[4 * i + 3] = v.w;
    }
  }

  __syncthreads();

  // min over this thread's windows of (xnorm_w - 2*dot(x_w, s_n)).
  float best = FLT_MAX;
  const int w0 = wslot * (WPB / 2);
  for (int wi = 0; wi < WPB / 2; ++wi) {
    const float* xr = xs + (size_t)(w0 + wi) * L;
    float a0 = 0.f, a1 = 0.f, a2 = 0.f, a3 = 0.f;  // 4 chains for ILP
#pragma unroll
    for (int l = 0; l < L; l += 4) {
      // Wave-uniform address -> LDS broadcast read, conflict-free.
      float4 xv = *(const float4*)(xr + l);
      a0 = fmaf(xv.x, s[l + 0], a0);
      a1 = fmaf(xv.y, s[l + 1], a1);
      a2 = fmaf(xv.z, s[l + 2], a2);
      a3 = fmaf(xv.w, s[l + 3], a3);
    }
    float dot = (a0 + a1) + (a2 + a3);
    best = fminf(best, fmaf(-2.f, dot, xnorm_s[w0 + wi]));
  }

  // Combine the two window-slots for each shapelet.
  __syncthreads();
  if (wslot == 1) comb[n] = best;
  __syncthreads();
  if (wslot == 0) {
    part[((size_t)b * NCHUNKS + c) * N + n] = fminf(best, comb[n]);
  }
}

// Kernel 2: min over chunks -> +||s_n||^2 -> sqrt -> dot(cls_w) -> sigmoid.
// grid = B, block = 128 (one thread per shapelet).
template <int NCHUNKS>
__global__ __launch_bounds__(128) void shapelet_head_kernel(
    const float* __restrict__ part, const float* __restrict__ shp,
    const float* __restrict__ cls_w, const float* __restrict__ cls_b,
    float* __restrict__ out) {
  const int b = blockIdx.x;
  const int n = threadIdx.x;  // 0..127

  float m = FLT_MAX;
#pragma unroll
  for (int c = 0; c < NCHUNKS; ++c)
    m = fminf(m, part[((size_t)b * NCHUNKS + c) * N + n]);

  // ||s_n||^2 (recomputed per block; 64 blocks x 32 KB from L2 — trivial).
  float sn = 0.f;
  {
    const float4* sg = (const float4*)(shp + (size_t)n * L);
#pragma unroll
    for (int i = 0; i < L / 4; ++i) {
      float4 v = sg[i];
      sn = fmaf(v.x, v.x, sn);
      sn = fmaf(v.y, v.y, sn);
      sn = fmaf(v.z, v.z, sn);
      sn = fmaf(v.w, v.w, sn);
    }
  }

  float d2 = fmaxf(m + sn, 0.f);  // guard fp rounding before sqrt
  float v = sqrtf(d2) * cls_w[n];

  // Sum over 128 threads: wave64 shuffle reduce, then combine 2 waves.
#pragma unroll
  for (int off = 32; off > 0; off >>= 1) v += __shfl_down(v, off, 64);

  __shared__ float red[2];
  if ((n & 63) == 0) red[n >> 6] = v;
  __syncthreads();
  if (n == 0) {
    float z = red[0] + red[1] + cls_b[0];
    out[b] = 1.0f / (1.0f + expf(-z));
  }
}

template <int NCHUNKS>
static void launch_impl(const float* x, const float* shp, const float* cls_w,
                        const float* cls_b, float* out, float* part,
                        hipStream_t stream) {
  shapelet_min_kernel<NCHUNKS><<<B * NCHUNKS, 256, 0, stream>>>(x, shp, part);
  shapelet_head_kernel<NCHUNKS>
      <<<B, 128, 0, stream>>>(part, shp, cls_w, cls_b, out);
}

extern "C" void kernel_launch(void* const* d_in, const int* in_sizes, int n_in,
                              void* d_out, int out_size, void* d_ws,
                              size_t ws_size, hipStream_t stream) {
  const float* x = (const float*)d_in[0];      // [B, W, L]
  const float* shp = (const float*)d_in[1];    // [N, L]
  const float* cls_w = (const float*)d_in[2];  // [1, N]
  const float* cls_b = (const float*)d_in[3];  // [1]
  float* out = (float*)d_out;                  // [B, 1]
  float* part = (float*)d_ws;                  // [B, NCHUNKS, N]

  const size_t per_chunk = (size_t)B * N * sizeof(float);  // 32 KB
  if (ws_size >= 16 * per_chunk) {
    launch_impl<16>(x, shp, cls_w, cls_b, out, part, stream);
  } else if (ws_size >= 8 * per_chunk) {
    launch_impl<8>(x, shp, cls_w, cls_b, out, part, stream);
  } else if (ws_size >= 4 * per_chunk) {
    launch_impl<4>(x, shp, cls_w, cls_b, out, part, stream);
  } else {
    launch_impl<1>(x, shp, cls_w, cls_b, out, part, stream);
  }
}